// Round 6
// baseline (1019.454 us; speedup 1.0000x reference)
//
#include <hip/hip_runtime.h>
#include <hip/hip_fp16.h>

typedef _Float16 f16;
typedef _Float16 f16x8 __attribute__((ext_vector_type(8)));
typedef float f32x4 __attribute__((ext_vector_type(4)));

#define B_SZ   4096
#define T_SZ   32
#define VOCAB  10000
#define E_SZ   300
#define H_SZ   300
#define KP     320          // embT row width (10x32)
#define GP     304          // per-gate padded N (19x16)
#define G4     1216         // 4*GP
#define LDA    328          // hbuf/xbuf row stride f16
#define LDG    1224         // gates row stride f16
#define ROWS   16           // batch rows per block
#define NBLK   (B_SZ/ROWS)  // 256 blocks -> 1 per CU

__device__ __forceinline__ float sigmoid_f(float x) {
    return 1.f / (1.f + __expf(-x));
}
__device__ __forceinline__ float tanh_f(float x) {
    x = fminf(fmaxf(x, -15.f), 15.f);
    float e = __expf(2.f * x);
    return (e - 1.f) / (e + 1.f);
}

// P0: embed_w f32 [V][300] -> embT f16 [V][320] zero-padded
__global__ void kP0(const float* __restrict__ ew, f16* __restrict__ embT) {
    int v = blockIdx.x, k = threadIdx.x;           // 320 threads
    embT[(size_t)v * KP + k] = (k < E_SZ) ? (f16)ew[(size_t)v * E_SZ + k] : (f16)0.f;
}

// kPW2: pack weights into MFMA-B-fragment order, coalesced.
// Wpk block (gate,nt,k) = 1024 B; lane (c,q) holds W[n=gate*300+nt*16+c][kk=k*32+q*8..+7]
// kk<320 -> W_hh col kk, kk>=320 -> W_ih col kk-320 (zero-padded).
__global__ void kPW2(const float* __restrict__ wih, const float* __restrict__ whh,
                     const float* __restrict__ bih, const float* __restrict__ bhh,
                     f16* __restrict__ Wpk, float* __restrict__ biasp) {
    int bid = blockIdx.x;                          // 0..1519 = (gate*19+nt)*20+k
    int lane = threadIdx.x;                        // 64
    int k = bid % 20, ntg = bid / 20;
    int nt = ntg % 19, gate = ntg / 19;
    int c = lane & 15, q = lane >> 4;
    int j = nt * 16 + c;                           // 0..303
    int src = gate * H_SZ + j;
    f16 vals[8];
#pragma unroll
    for (int jj = 0; jj < 8; ++jj) {
        int kk = k * 32 + q * 8 + jj;
        float v = 0.f;
        if (j < H_SZ) {
            if (kk < KP) { if (kk < H_SZ) v = whh[(size_t)src * H_SZ + kk]; }
            else { int kx = kk - KP; if (kx < E_SZ) v = wih[(size_t)src * E_SZ + kx]; }
        }
        vals[jj] = (f16)v;
    }
    *(f16x8*)(Wpk + ((size_t)bid * 64 + lane) * 8) = *(const f16x8*)vals;
    if (k == 0 && q == 0)
        biasp[gate * GP + j] = (j < H_SZ) ? (bih[src] + bhh[src]) : 0.f;
}

// P2: weight-normed classifier W = g * v / ||v||  -> Wc f32 [2][GP]
__global__ void kP2(const float* __restrict__ cls_v, const float* __restrict__ cls_g,
                    float* __restrict__ Wc) {
    int lane = threadIdx.x;                        // 64
    for (int cl = 0; cl < 2; ++cl) {
        float s = 0.f;
        for (int j = lane; j < H_SZ; j += 64) { float v = cls_v[cl * H_SZ + j]; s += v * v; }
        for (int off = 32; off; off >>= 1) s += __shfl_down(s, off);
        float nrm = sqrtf(__shfl(s, 0));
        float scale = cls_g[cl] / nrm;
        for (int j = lane; j < H_SZ; j += 64) Wc[cl * GP + j] = cls_v[cl * H_SZ + j] * scale;
    }
}

// kR5: fused LSTM recurrence. 256 blocks x 1024 thr (16 waves), 16 rows/block.
// Wave (gate = w>>2, q4 = w&3): n-quarter of one gate, TM=1.
// Weight stream double-buffered in registers (10-frag batches); A-frags re-read
// from LDS per nt-tile to stay under the 128-VGPR cap.
__global__ __launch_bounds__(1024, 4) void kR5(const int* __restrict__ cap,
                                               const int* __restrict__ cap_len,
                                               const f16* __restrict__ embT,
                                               const f16* __restrict__ Wpk,
                                               const float* __restrict__ biasp,
                                               float* __restrict__ hlast) {
    extern __shared__ __align__(16) char smem[];
    f16*   hbuf  = (f16*)smem;                              // 16*LDA*2 = 10496
    f16*   xbuf  = (f16*)(smem + 10496);                    // 10496
    f16*   gates = (f16*)(smem + 20992);                    // 16*LDG*2 = 39168
    float* cbuf  = (float*)(smem + 20992 + 39168);          // 16*320*4 = 20480
    float* biasL = (float*)(smem + 20992 + 39168 + 20480);  // 4864
    int*   capv  = (int*)(smem + 20992 + 39168 + 20480 + 4864); // 16*32*4 = 2048
    int*   lens  = capv + ROWS * T_SZ;                      // 64
    int tid = threadIdx.x;
    int b0 = blockIdx.x * ROWS;
    if (tid < ROWS) lens[tid] = cap_len[b0 + tid];
    for (int i = tid; i < ROWS * T_SZ; i += 1024) capv[i] = cap[(size_t)b0 * T_SZ + i];
    for (int i = tid; i < ROWS * LDA; i += 1024) hbuf[i] = (f16)0.f;  // pads stay 0
    for (int i = tid; i < ROWS * 320; i += 1024) cbuf[i] = 0.f;
    for (int i = tid; i < G4; i += 1024) biasL[i] = biasp[i];
    __syncthreads();
    // stage x for t=0
    if (tid < ROWS * 40) {
        int m = tid / 40, c8 = tid - m * 40;
        int v = capv[m * T_SZ + 0];
        *(f16x8*)(xbuf + m * LDA + c8 * 8) = *(const f16x8*)(embT + (size_t)v * KP + c8 * 8);
    }
    __syncthreads();
    int wave = tid >> 6, lane = tid & 63;
    int c = lane & 15, q = lane >> 4;
    int gate = wave >> 2, q4 = wave & 3;
    int nt0 = q4 * 5, cnt = (q4 == 3) ? 4 : 5;     // 19 = 5+5+5+4
    const f16* wp0 = Wpk + ((size_t)((gate * 19 + nt0) * 20) * 64 + lane) * 8;
    const f16* hrow = hbuf + c * LDA + q * 8;
    const f16* xrow = xbuf + c * LDA + q * 8;

    for (int t = 0; t < T_SZ; ++t) {
        // --- phase 1: gate preacts, K=640 fused [h|x], register-dbuf weight stream ---
        const f16* wp = wp0;
        f16x8 bh[10], bx[10];
        // prologue: issue all 10 h-part loads of nt=0
#pragma unroll
        for (int k = 0; k < 10; ++k)
            bh[k] = *(const f16x8*)(wp + (size_t)k * 512);
#pragma unroll 1
        for (int nt = 0; nt < cnt; ++nt) {
            int ncol = gate * GP + (nt0 + nt) * 16 + c;
            float bia = biasL[ncol];
            f32x4 acc = {bia, bia, bia, bia};
            // issue x-part loads (batched) before consuming bh
#pragma unroll
            for (int k = 0; k < 10; ++k)
                bx[k] = *(const f16x8*)(wp + (size_t)(10 + k) * 512);
            // consume h-part: A-frag from LDS, MFMA against bh
#pragma unroll
            for (int k = 0; k < 10; ++k) {
                f16x8 a = *(const f16x8*)(hrow + k * 32);
                acc = __builtin_amdgcn_mfma_f32_16x16x32_f16(a, bh[k], acc, 0, 0, 0);
            }
            // issue next tile's h-part loads before consuming bx
            const f16* wpn = wp + 20 * 512;
            if (nt + 1 < cnt) {
#pragma unroll
                for (int k = 0; k < 10; ++k)
                    bh[k] = *(const f16x8*)(wpn + (size_t)k * 512);
            }
            // consume x-part
#pragma unroll
            for (int k = 0; k < 10; ++k) {
                f16x8 a = *(const f16x8*)(xrow + k * 32);
                acc = __builtin_amdgcn_mfma_f32_16x16x32_f16(a, bx[k], acc, 0, 0, 0);
            }
#pragma unroll
            for (int r = 0; r < 4; ++r)
                gates[(q * 4 + r) * LDG + ncol] = (f16)acc[r];
            wp = wpn;
        }
        __syncthreads();
        // --- phase 2: elementwise cell update + stage x(t+1) ---
        int tp1 = t + 1;
        if (tp1 < T_SZ && tid < ROWS * 40) {
            int m = tid / 40, c8 = tid - m * 40;
            int v = capv[m * T_SZ + tp1];
            *(f16x8*)(xbuf + m * LDA + c8 * 8) = *(const f16x8*)(embT + (size_t)v * KP + c8 * 8);
        }
#pragma unroll
        for (int it = 0; it < 5; ++it) {
            int idx = tid + it * 1024;             // 0..5119 = 16*320
            int m = idx / 320, j = idx - m * 320;
            if (j < H_SZ) {
                const f16* gr = gates + m * LDG;
                float gi = (float)gr[j];
                float gf = (float)gr[GP + j];
                float gg = (float)gr[2 * GP + j];
                float go = (float)gr[3 * GP + j];
                float ii = sigmoid_f(gi);
                float ff = sigmoid_f(gf);
                float gt = tanh_f(gg);
                float oo = sigmoid_f(go);
                float cn = ff * cbuf[idx] + ii * gt;
                cbuf[idx] = cn;
                float hh = oo * tanh_f(cn);
                hbuf[m * LDA + j] = (f16)hh;
                if (t == lens[m] - 1) hlast[(size_t)(b0 + m) * GP + j] = hh;
            }
        }
        __syncthreads();
    }
}

// kC: out[row][cl] = hlast[row] . Wc[cl] + cls_b[cl]
__global__ void kC(const float* __restrict__ hlast, const float* __restrict__ Wc,
                   const float* __restrict__ cls_b, float* __restrict__ out) {
    int row = blockIdx.x, lane = threadIdx.x;      // 64 threads
    const float* h = hlast + (size_t)row * GP;
    float s0 = 0.f, s1 = 0.f;
    for (int j = lane; j < H_SZ; j += 64) {
        float hv = h[j];
        s0 += hv * Wc[j];
        s1 += hv * Wc[GP + j];
    }
    for (int off = 32; off; off >>= 1) {
        s0 += __shfl_down(s0, off);
        s1 += __shfl_down(s1, off);
    }
    if (lane == 0) {
        out[row * 2 + 0] = s0 + cls_b[0];
        out[row * 2 + 1] = s1 + cls_b[1];
    }
}

extern "C" void kernel_launch(void* const* d_in, const int* in_sizes, int n_in,
                              void* d_out, int out_size, void* d_ws, size_t ws_size,
                              hipStream_t stream) {
    const int*   cap     = (const int*)d_in[0];
    const int*   cap_len = (const int*)d_in[1];
    const float* embed_w = (const float*)d_in[2];
    const float* W_ih    = (const float*)d_in[3];
    const float* W_hh    = (const float*)d_in[4];
    const float* b_ih    = (const float*)d_in[5];
    const float* b_hh    = (const float*)d_in[6];
    const float* cls_v   = (const float*)d_in[7];
    const float* cls_g   = (const float*)d_in[8];
    const float* cls_b   = (const float*)d_in[9];
    float* out = (float*)d_out;

    char* w = (char*)d_ws;
    size_t off = 0;
    auto alloc = [&](size_t bytes) -> void* {
        void* p = w + off;
        off += (bytes + 255) & ~(size_t)255;
        return p;
    };
    f16*   embT  = (f16*)alloc((size_t)VOCAB * KP * sizeof(f16));      // 6.4 MB
    f16*   Wpk   = (f16*)alloc((size_t)1520 * 64 * 8 * sizeof(f16));   // 1.56 MB
    float* biasp = (float*)alloc((size_t)G4 * sizeof(float));
    float* Wc    = (float*)alloc((size_t)2 * GP * sizeof(float));
    float* hlast = (float*)alloc((size_t)B_SZ * GP * sizeof(float));   // 5.0 MB

    // dynamic LDS: 87,616 B. Host-side config op, capture-safe.
    static const int smem_bytes = 20992 + 39168 + 20480 + 4864 + 2048 + 64;
    (void)hipFuncSetAttribute((const void*)kR5,
                              hipFuncAttributeMaxDynamicSharedMemorySize, smem_bytes);

    kP0<<<VOCAB, KP, 0, stream>>>(embed_w, embT);
    kPW2<<<1520, 64, 0, stream>>>(W_ih, W_hh, b_ih, b_hh, Wpk, biasp);
    kP2<<<1, 64, 0, stream>>>(cls_v, cls_g, Wc);
    kR5<<<NBLK, 1024, smem_bytes, stream>>>(cap, cap_len, embT, Wpk, biasp, hlast);
    kC<<<B_SZ, 64, 0, stream>>>(hlast, Wc, cls_b, out);
}

// Round 7
// 724.651 us; speedup vs baseline: 1.4068x; 1.4068x over previous
//
#include <hip/hip_runtime.h>
#include <hip/hip_fp16.h>

typedef _Float16 f16;
typedef _Float16 f16x8 __attribute__((ext_vector_type(8)));
typedef float f32x4 __attribute__((ext_vector_type(4)));

#define B_SZ   4096
#define T_SZ   32
#define VOCAB  10000
#define E_SZ   300
#define H_SZ   300
#define KP     320          // embT row width (10x32)
#define GP     304          // per-gate padded N (19x16)
#define G4     1216         // 4*GP
#define LDA    328          // hbuf/xbuf row stride f16 (16B-aligned rows)
#define LDG    1224         // gates row stride f16
#define ROWS   16           // batch rows per block
#define NBLK   (B_SZ/ROWS)  // 256 blocks -> 1 per CU

__device__ __forceinline__ float sigmoid_f(float x) {
    return 1.f / (1.f + __expf(-x));
}
__device__ __forceinline__ float tanh_f(float x) {
    x = fminf(fmaxf(x, -15.f), 15.f);
    float e = __expf(2.f * x);
    return (e - 1.f) / (e + 1.f);
}

// P0: embed_w f32 [V][300] -> embT f16 [V][320] zero-padded
__global__ void kP0(const float* __restrict__ ew, f16* __restrict__ embT) {
    int v = blockIdx.x, k = threadIdx.x;           // 320 threads
    embT[(size_t)v * KP + k] = (k < E_SZ) ? (f16)ew[(size_t)v * E_SZ + k] : (f16)0.f;
}

// kPW2: pack weights into MFMA-B-fragment order, coalesced.
// Wpk block (gate,nt,k) = 1024 B; lane (c,q) holds W[n=gate*300+nt*16+c][kk=k*32+q*8..+7]
// kk<320 -> W_hh col kk, kk>=320 -> W_ih col kk-320 (zero-padded).
__global__ void kPW2(const float* __restrict__ wih, const float* __restrict__ whh,
                     const float* __restrict__ bih, const float* __restrict__ bhh,
                     f16* __restrict__ Wpk, float* __restrict__ biasp) {
    int bid = blockIdx.x;                          // 0..1519 = (gate*19+nt)*20+k
    int lane = threadIdx.x;                        // 64
    int k = bid % 20, ntg = bid / 20;
    int nt = ntg % 19, gate = ntg / 19;
    int c = lane & 15, q = lane >> 4;
    int j = nt * 16 + c;                           // 0..303
    int src = gate * H_SZ + j;
    f16 vals[8];
#pragma unroll
    for (int jj = 0; jj < 8; ++jj) {
        int kk = k * 32 + q * 8 + jj;
        float v = 0.f;
        if (j < H_SZ) {
            if (kk < KP) { if (kk < H_SZ) v = whh[(size_t)src * H_SZ + kk]; }
            else { int kx = kk - KP; if (kx < E_SZ) v = wih[(size_t)src * E_SZ + kx]; }
        }
        vals[jj] = (f16)v;
    }
    *(f16x8*)(Wpk + ((size_t)bid * 64 + lane) * 8) = *(const f16x8*)vals;
    if (k == 0 && q == 0)
        biasp[gate * GP + j] = (j < H_SZ) ? (bih[src] + bhh[src]) : 0.f;
}

// P2: weight-normed classifier W = g * v / ||v||  -> Wc f32 [2][GP]
__global__ void kP2(const float* __restrict__ cls_v, const float* __restrict__ cls_g,
                    float* __restrict__ Wc) {
    int lane = threadIdx.x;                        // 64
    for (int cl = 0; cl < 2; ++cl) {
        float s = 0.f;
        for (int j = lane; j < H_SZ; j += 64) { float v = cls_v[cl * H_SZ + j]; s += v * v; }
        for (int off = 32; off; off >>= 1) s += __shfl_down(s, off);
        float nrm = sqrtf(__shfl(s, 0));
        float scale = cls_g[cl] / nrm;
        for (int j = lane; j < H_SZ; j += 64) Wc[cl * GP + j] = cls_v[cl * H_SZ + j] * scale;
    }
}

// kR6: fused LSTM recurrence. 256 blocks x 1024 thr (16 waves), 16 rows/block.
// Wave (gate, n-quarter); weight stream = contiguous 1KB blocks, consumed through
// a 5-slot rotating register pipeline (prefetch distance 5). waves_per_eu(4,4)
// pins the VGPR budget at 128 so the pipeline cannot spill.
__global__ __attribute__((amdgpu_waves_per_eu(4, 4))) __launch_bounds__(1024)
void kR6(const int* __restrict__ cap,
         const int* __restrict__ cap_len,
         const f16* __restrict__ embT,
         const f16* __restrict__ Wpk,
         const float* __restrict__ biasp,
         float* __restrict__ hlast) {
    extern __shared__ __align__(16) char smem[];
    f16*   hbuf  = (f16*)smem;                          // 16*328*2 = 10496
    f16*   xbuf  = (f16*)(smem + 10496);                // 10496
    f16*   gates = (f16*)(smem + 20992);                // 16*1224*2 = 39168
    float* biasL = (float*)(smem + 60160);              // 4864
    int*   capv  = (int*)(smem + 65024);                // 16*32*4 = 2048
    int*   lens  = (int*)(smem + 67072);                // 64
    int tid = threadIdx.x;
    int b0 = blockIdx.x * ROWS;
    if (tid < ROWS) lens[tid] = cap_len[b0 + tid];
    for (int i = tid; i < ROWS * T_SZ; i += 1024) capv[i] = cap[(size_t)b0 * T_SZ + i];
    for (int i = tid; i < ROWS * LDA; i += 1024) hbuf[i] = (f16)0.f;  // pads stay 0
    for (int i = tid; i < G4; i += 1024) biasL[i] = biasp[i];
    __syncthreads();
    // stage x for t=0
    if (tid < ROWS * 40) {
        int m = tid / 40, c8 = tid - m * 40;
        int v = capv[m * T_SZ + 0];
        *(f16x8*)(xbuf + m * LDA + c8 * 8) = *(const f16x8*)(embT + (size_t)v * KP + c8 * 8);
    }
    __syncthreads();
    int wave = tid >> 6, lane = tid & 63;
    int c = lane & 15, q = lane >> 4;
    int gate = wave >> 2, q4 = wave & 3;
    int nt0 = q4 * 5, cnt = (q4 == 3) ? 4 : 5;     // 19 = 5+5+5+4
    const f16* wp0 = Wpk + ((size_t)((gate * 19 + nt0) * 20) * 64 + lane) * 8;
    const f16* hrow = hbuf + c * LDA + q * 8;
    const f16* xrow = xbuf + c * LDA + q * 8;
    float creg[5];                                  // per-thread c-state, idx map fixed over t
#pragma unroll
    for (int i = 0; i < 5; ++i) creg[i] = 0.f;

    for (int t = 0; t < T_SZ; ++t) {
        // --- phase 1: gate preacts, K=640 fused [h|x] ---
        // h-part A-frags register-resident for the whole step
        f16x8 afr[10];
#pragma unroll
        for (int k = 0; k < 10; ++k)
            afr[k] = *(const f16x8*)(hrow + k * 32);
        // weight pipeline prologue: slots 0..4 <- stream blocks 0..4
        f16x8 buf[5];
#pragma unroll
        for (int s = 0; s < 5; ++s)
            buf[s] = *(const f16x8*)(wp0 + (size_t)s * 512);
#pragma unroll 1
        for (int nt = 0; nt < cnt; ++nt) {
            int base = nt * 20;
            int ncol = gate * GP + (nt0 + nt) * 16 + c;
            float bia = biasL[ncol];
            f32x4 acc = {bia, bia, bia, bia};
#pragma unroll
            for (int k = 0; k < 20; ++k) {
                f16x8 a;
                if (k < 10) a = afr[k];
                else        a = *(const f16x8*)(xrow + (k - 10) * 32);
                acc = __builtin_amdgcn_mfma_f32_16x16x32_f16(a, buf[k % 5], acc, 0, 0, 0);
                // prefetch stream block base+k+5 into the slot just consumed
                if (nt + 1 < cnt || k < 15)
                    buf[k % 5] = *(const f16x8*)(wp0 + (size_t)(base + k + 5) * 512);
            }
#pragma unroll
            for (int r = 0; r < 4; ++r)
                gates[(q * 4 + r) * LDG + ncol] = (f16)acc[r];
        }
        __syncthreads();
        // --- phase 2: elementwise cell update + stage x(t+1) ---
        int tp1 = t + 1;
        if (tp1 < T_SZ && tid < ROWS * 40) {
            int m = tid / 40, c8 = tid - m * 40;
            int v = capv[m * T_SZ + tp1];
            *(f16x8*)(xbuf + m * LDA + c8 * 8) = *(const f16x8*)(embT + (size_t)v * KP + c8 * 8);
        }
#pragma unroll
        for (int it = 0; it < 5; ++it) {
            int idx = tid + it * 1024;             // 0..5119 = 16*320
            int m = idx / 320, j = idx - m * 320;
            if (j < H_SZ) {
                const f16* gr = gates + m * LDG;
                float gi = (float)gr[j];
                float gf = (float)gr[GP + j];
                float gg = (float)gr[2 * GP + j];
                float go = (float)gr[3 * GP + j];
                float ii = sigmoid_f(gi);
                float ff = sigmoid_f(gf);
                float gt = tanh_f(gg);
                float oo = sigmoid_f(go);
                float cn = ff * creg[it] + ii * gt;
                creg[it] = cn;
                float hh = oo * tanh_f(cn);
                hbuf[m * LDA + j] = (f16)hh;
                if (t == lens[m] - 1) hlast[(size_t)(b0 + m) * GP + j] = hh;
            }
        }
        __syncthreads();
    }
}

// kC: out[row][cl] = hlast[row] . Wc[cl] + cls_b[cl]
__global__ void kC(const float* __restrict__ hlast, const float* __restrict__ Wc,
                   const float* __restrict__ cls_b, float* __restrict__ out) {
    int row = blockIdx.x, lane = threadIdx.x;      // 64 threads
    const float* h = hlast + (size_t)row * GP;
    float s0 = 0.f, s1 = 0.f;
    for (int j = lane; j < H_SZ; j += 64) {
        float hv = h[j];
        s0 += hv * Wc[j];
        s1 += hv * Wc[GP + j];
    }
    for (int off = 32; off; off >>= 1) {
        s0 += __shfl_down(s0, off);
        s1 += __shfl_down(s1, off);
    }
    if (lane == 0) {
        out[row * 2 + 0] = s0 + cls_b[0];
        out[row * 2 + 1] = s1 + cls_b[1];
    }
}

extern "C" void kernel_launch(void* const* d_in, const int* in_sizes, int n_in,
                              void* d_out, int out_size, void* d_ws, size_t ws_size,
                              hipStream_t stream) {
    const int*   cap     = (const int*)d_in[0];
    const int*   cap_len = (const int*)d_in[1];
    const float* embed_w = (const float*)d_in[2];
    const float* W_ih    = (const float*)d_in[3];
    const float* W_hh    = (const float*)d_in[4];
    const float* b_ih    = (const float*)d_in[5];
    const float* b_hh    = (const float*)d_in[6];
    const float* cls_v   = (const float*)d_in[7];
    const float* cls_g   = (const float*)d_in[8];
    const float* cls_b   = (const float*)d_in[9];
    float* out = (float*)d_out;

    char* w = (char*)d_ws;
    size_t off = 0;
    auto alloc = [&](size_t bytes) -> void* {
        void* p = w + off;
        off += (bytes + 255) & ~(size_t)255;
        return p;
    };
    f16*   embT  = (f16*)alloc((size_t)VOCAB * KP * sizeof(f16));      // 6.4 MB
    f16*   Wpk   = (f16*)alloc((size_t)1520 * 64 * 8 * sizeof(f16));   // 1.56 MB
    float* biasp = (float*)alloc((size_t)G4 * sizeof(float));
    float* Wc    = (float*)alloc((size_t)2 * GP * sizeof(float));
    float* hlast = (float*)alloc((size_t)B_SZ * GP * sizeof(float));   // 5.0 MB

    // dynamic LDS: 67,136 B. Host-side config op, capture-safe.
    static const int smem_bytes = 67072 + 64;
    (void)hipFuncSetAttribute((const void*)kR6,
                              hipFuncAttributeMaxDynamicSharedMemorySize, smem_bytes);

    kP0<<<VOCAB, KP, 0, stream>>>(embed_w, embT);
    kPW2<<<1520, 64, 0, stream>>>(W_ih, W_hh, b_ih, b_hh, Wpk, biasp);
    kP2<<<1, 64, 0, stream>>>(cls_v, cls_g, Wc);
    kR6<<<NBLK, 1024, smem_bytes, stream>>>(cap, cap_len, embT, Wpk, biasp, hlast);
    kC<<<B_SZ, 64, 0, stream>>>(hlast, Wc, cls_b, out);
}